// Round 6
// baseline (655.525 us; speedup 1.0000x reference)
//
#include <hip/hip_runtime.h>
#include <stdint.h>

typedef float  f32x4   __attribute__((ext_vector_type(4)));
typedef float  f32x16  __attribute__((ext_vector_type(16)));
typedef __bf16 bf16x8  __attribute__((ext_vector_type(8)));
typedef unsigned int   u32;
typedef unsigned short u16;
typedef unsigned long long u64;
typedef u32 u32x4 __attribute__((ext_vector_type(4)));

#define M_TOT 8192
#define N_TOT 4096
#define K_DIN 4096
#define RANK  32
#define KCAT  8320         // 4096 (xq|wq) + 4096 (xb|ws) + 128 (t|lb zero-padded)
#define NTILE 130          // KCAT / 64
#define KLAST 8256         // (NTILE-1)*64

__device__ __forceinline__ u16 f2bf(float f) {
  union { float f; u32 u; } v; v.f = f;
  u32 r = v.u + 0x7fffu + ((v.u >> 16) & 1u);
  return (u16)(r >> 16);
}

// ---- P0: a_sb[r][k] = bf16(lora_a[r][k] * smooth[k])  (32x4096)
__global__ void prep_as_k(const float* __restrict__ la, const float* __restrict__ ss,
                          u16* __restrict__ asb) {
  int i = blockIdx.x * 256 + threadIdx.x;
  f32x4 v = ((const f32x4*)la)[i];
  f32x4 s = ((const f32x4*)ss)[i & 1023];
  f32x4 p = v * s;
  alignas(8) u16 o[4] = { f2bf(p[0]), f2bf(p[1]), f2bf(p[2]), f2bf(p[3]) };
  *(u64*)(asb + 4 * (size_t)i) = *(const u64*)o;
}

// ---- weight cast into B-concat [4096][KCAT] at column offset colofs
__global__ void cvt_w_k(const float* __restrict__ in, u16* __restrict__ Bb, int colofs) {
  int i = blockIdx.x * 256 + threadIdx.x;          // 4M float4s
  f32x4 v = ((const f32x4*)in)[i];
  int r = i >> 10, c = (i & 1023) * 4;
  alignas(8) u16 o[4] = { f2bf(v[0]), f2bf(v[1]), f2bf(v[2]), f2bf(v[3]) };
  *(u64*)(Bb + (size_t)r * KCAT + colofs + c) = *(const u64*)o;
}

// ---- lora_b [4096][32] -> B-concat cols 8192..8223; zero cols 8224..8319
__global__ void cvt_lb_k(const float* __restrict__ in, u16* __restrict__ Bb) {
  int i = blockIdx.x * 256 + threadIdx.x;          // 32768 float4s
  f32x4 v = ((const f32x4*)in)[i];
  int row = i >> 3, c = (i & 7) * 4;
  alignas(8) u16 o[4] = { f2bf(v[0]), f2bf(v[1]), f2bf(v[2]), f2bf(v[3]) };
  u16* rp = Bb + (size_t)row * KCAT;
  *(u64*)(rp + 2 * K_DIN + c) = *(const u64*)o;
  u16* zp = rp + 2 * K_DIN + RANK + (i & 7) * 12;  // 8 threads x 12 cols = 96 zeros
  *(u64*)(zp + 0) = 0; *(u64*)(zp + 4) = 0; *(u64*)(zp + 8) = 0;
}

// ---- P1: smooth+quant -> A-concat cols 0..4095 (xq); raw bf16 -> cols 4096..8191 (xb)
__global__ void prep_x_k(const float* __restrict__ x, const float* __restrict__ ss,
                         u16* __restrict__ Ab) {
  int m = blockIdx.x;
  int t = threadIdx.x;
  const f32x4* xp = (const f32x4*)(x + (size_t)m * K_DIN + t * 16);
  const f32x4* sp = (const f32x4*)(ss + t * 16);
  float xs[16];
  alignas(16) u16 rb[16], qb[16];
  float amax = 0.0f;
  #pragma unroll
  for (int i = 0; i < 4; ++i) {
    f32x4 a = xp[i], s = sp[i];
    #pragma unroll
    for (int j = 0; j < 4; ++j) {
      float xr = a[j];
      float v  = xr * s[j];
      xs[i*4+j] = v;
      amax = fmaxf(amax, fabsf(v));
      rb[i*4+j] = f2bf(xr);
    }
  }
  amax = fmaxf(amax, 1e-12f);
  float scale = amax / 7.0f;                       // IEEE div, matches numpy
  #pragma unroll
  for (int i = 0; i < 16; ++i) {
    float r = rintf(xs[i] / scale);                // RNE, matches jnp.round
    r = fminf(7.0f, fmaxf(-7.0f, r));
    qb[i] = f2bf(r * scale);
  }
  u16* qo = Ab + (size_t)m * KCAT + t * 16;
  ((u32x4*)qo)[0] = ((const u32x4*)qb)[0];
  ((u32x4*)qo)[1] = ((const u32x4*)qb)[1];
  u16* ro = qo + K_DIN;
  ((u32x4*)ro)[0] = ((const u32x4*)rb)[0];
  ((u32x4*)ro)[1] = ((const u32x4*)rb)[1];
}

// ---- P2: t = xb @ a_s^T via MFMA -> A-concat cols 8192..8223; zero 8224..8319
__global__ __launch_bounds__(256)
void lora_t_mfma_k(u16* __restrict__ Ab, const u16* __restrict__ asb) {
  const int wave = threadIdx.x >> 6;
  const int lane = threadIdx.x & 63;
  const int lr = lane & 15, lg = lane >> 4;
  const int m0 = blockIdx.x * 64 + wave * 16;
  f32x4 acc0 = {}, acc1 = {};
  for (int k0 = 0; k0 < K_DIN; k0 += 32) {
    bf16x8 a  = *(const bf16x8*)(Ab + (size_t)(m0 + lr) * KCAT + K_DIN + k0 + lg * 8);
    bf16x8 b0 = *(const bf16x8*)(asb + (size_t)lr        * K_DIN + k0 + lg * 8);
    bf16x8 b1 = *(const bf16x8*)(asb + (size_t)(16 + lr) * K_DIN + k0 + lg * 8);
    acc0 = __builtin_amdgcn_mfma_f32_16x16x32_bf16(a, b0, acc0, 0, 0, 0);
    acc1 = __builtin_amdgcn_mfma_f32_16x16x32_bf16(a, b1, acc1, 0, 0, 0);
  }
  #pragma unroll
  for (int j = 0; j < 4; ++j) {
    const int row = m0 + lg * 4 + j;
    Ab[(size_t)row * KCAT + 2 * K_DIN + lr]      = f2bf(acc0[j]);
    Ab[(size_t)row * KCAT + 2 * K_DIN + 16 + lr] = f2bf(acc1[j]);
  }
  // zero pad cols 8224..8319 for this block's 64 rows (4 threads/row x 24 cols)
  const int zr = blockIdx.x * 64 + (threadIdx.x >> 2);
  u16* zp = Ab + (size_t)zr * KCAT + 2 * K_DIN + RANK + (threadIdx.x & 3) * 24;
  #pragma unroll
  for (int q = 0; q < 6; ++q) *(u64*)(zp + q * 4) = 0;
}

// ============ main GEMM: 256x256 tile, BK=64, 8-phase, 32x32x16 MFMA ============
__device__ __forceinline__ void gld_lds16(const u16* g, u16* l) {
  __builtin_amdgcn_global_load_lds((const __attribute__((address_space(1))) u32*)g,
                                   (__attribute__((address_space(3))) u32*)l,
                                   16, 0, 0);
}

#define BAR()  __builtin_amdgcn_s_barrier()
#define VMW6() asm volatile("s_waitcnt vmcnt(6)" ::: "memory")
#define BUF1 32768

// ds-load A: 2 m-frags (32 rows each) x 4 k-slices; B: 1 n-frag x 4 slices
#define LDA32(bufel, mh) do { _Pragma("unroll")                                      \
  for (int ks_ = 0; ks_ < 4; ++ks_) { _Pragma("unroll")                              \
    for (int f_ = 0; f_ < 2; ++f_)                                                   \
      Ar[f_][ks_] = *(const bf16x8*)(smem + (bufel) + aoff + ((mh)*2+f_)*2048 + bofs[ks_]); \
  } } while (0)

#define LDB32(bufel, nh) do { _Pragma("unroll")                                      \
  for (int ks_ = 0; ks_ < 4; ++ks_)                                                  \
    Br[nh][ks_] = *(const bf16x8*)(smem + (bufel) + boff + (nh)*2048 + bofs[ks_]);    \
  } while (0)

// one C-quadrant: 2 m-frags x 1 n-frag x 4 k-slices = 8 MFMA (T5 setprio)
#define MMQ32(mh, nh) do {                                                           \
  __builtin_amdgcn_s_setprio(1);                                                     \
  _Pragma("unroll")                                                                  \
  for (int ks_ = 0; ks_ < 4; ++ks_) { _Pragma("unroll")                              \
    for (int f_ = 0; f_ < 2; ++f_)                                                   \
      acc[(mh)*2+f_][nh] = __builtin_amdgcn_mfma_f32_32x32x16_bf16(                  \
          Ar[f_][ks_], Br[nh][ks_], acc[(mh)*2+f_][nh], 0, 0, 0);                    \
  }                                                                                  \
  __builtin_amdgcn_s_setprio(0);                                                     \
} while (0)

__global__ __launch_bounds__(512, 2)
void gemm32_k(const u16* __restrict__ Ab, const u16* __restrict__ Bb,
              const float* __restrict__ bias, float* __restrict__ out) {
  extern __shared__ u16 smem[];           // 2 bufs x (A 16384 + B 16384) elems = 128 KiB
  const int tid  = threadIdx.x;
  const int wave = tid >> 6;
  const int lane = tid & 63;
  const int l31 = lane & 31, l5 = lane >> 5;
  const int wm = wave >> 2, wn = wave & 3;

  // T1: bijective XCD swizzle (512 % 8 == 0)
  const int wg  = blockIdx.x;
  const int swz = (wg & 7) * 64 + (wg >> 3);
  const int m0 = (swz >> 4) * 256;
  const int n0 = (swz & 15) * 256;

  // ds_read addressing: row-major [row][64] halves; 16B-block XOR swizzle (T2)
  // lane reads row = frag*32 + l31, k = ks*16 + l5*8 -> block (ks*2+l5) ^ (row&7)
  const int aoff = wm * 8192 + l31 * 64;
  const int boff = 16384 + wn * 4096 + l31 * 64;
  int bofs[4];
  #pragma unroll
  for (int ks = 0; ks < 4; ++ks) bofs[ks] = ((ks * 2 + l5) ^ (lane & 7)) * 8;

  // staging: thread t covers row tid>>3 (of 64-row issue), source col pre-swizzled
  const int srow = tid >> 3;
  const int scol = ((tid & 7) ^ (srow & 7)) * 8;
  const int woff = wave * 512;

  const u16* aRow = Ab + (size_t)(m0 + srow) * KCAT + scol;
  const u16* bRow = Bb + (size_t)(n0 + srow) * KCAT + scol;
  u16* dstA0 = smem + woff;            // buf0 A h=0 (h=1 at +8192; buf1 at +BUF1)
  u16* dstB0 = smem + 16384 + woff;

  bf16x8 Ar[2][4], Br[2][4];
  f32x16 acc[4][2] = {};

  auto stgA = [&](int kof, int h, int bufel) {
    u16* dst = dstA0 + bufel + h * 8192;
    gld_lds16(aRow + (size_t)(h * 128) * KCAT + kof, dst);
    gld_lds16(aRow + (size_t)(h * 128 + 64) * KCAT + kof, dst + 4096);
  };
  auto stgB = [&](int kof, int h, int bufel) {
    u16* dst = dstB0 + bufel + h * 8192;
    gld_lds16(bRow + (size_t)(h * 128) * KCAT + kof, dst);
    gld_lds16(bRow + (size_t)(h * 128 + 64) * KCAT + kof, dst + 4096);
  };

  // prologue: tile0 full (buf0), then t1.B0,B1,A0 (buf1); gate tile0 (oldest 8 of 14)
  stgA(0, 0, 0);     stgA(0, 1, 0);
  stgB(0, 0, 0);     stgB(0, 1, 0);
  stgB(64, 0, BUF1); stgB(64, 1, BUF1);
  stgA(64, 0, BUF1);
  VMW6();
  BAR();

  for (int it = 0; it < NTILE / 2; ++it) {
    const int ka = it * 128;
    int c2 = ka + 128, c3 = ka + 192;              // prefetch tiles a+2, a+3
    if (c2 > KLAST) c2 = KLAST;                    // tail: re-stage junk (never read)
    if (c3 > KLAST) c3 = KLAST;
    // P1: Q00(a) | stage b.A1 -> buf1 (buf1.A1 read-done prev P7)
    LDA32(0, 0); LDB32(0, 0);
    stgA(ka + 64, 1, BUF1);
    BAR(); MMQ32(0, 0); BAR();
    // P2: Q01(a) | stage (a+2).B0 -> buf0 (buf0.B0 read-done P1)
    LDB32(0, 1);
    stgB(c2, 0, 0);
    BAR(); MMQ32(0, 1); BAR();
    // P3: Q11(a) | stage (a+2).B1 -> buf0 (read-done P2)
    LDA32(0, 1);
    stgB(c2, 1, 0);
    BAR(); MMQ32(1, 1); BAR();
    // P4: Q10(a) | stage (a+2).A0 -> buf0 (read-done P1); gate tile b complete
    stgA(c2, 0, 0);
    BAR(); MMQ32(1, 0);
    VMW6();                 // oldest 8 of 14 = tile b; 6 in flight
    BAR();
    // P5: Q00(b) | stage (a+2).A1 -> buf0 (read-done P3)
    LDA32(BUF1, 0); LDB32(BUF1, 0);
    stgA(c2, 1, 0);
    BAR(); MMQ32(0, 0); BAR();
    // P6: Q01(b) | stage (a+3).B0 -> buf1 (buf1.B0 read-done P5)
    LDB32(BUF1, 1);
    stgB(c3, 0, BUF1);
    BAR(); MMQ32(0, 1); BAR();
    // P7: Q11(b) | stage (a+3).B1 -> buf1 (read-done P6)
    LDA32(BUF1, 1);
    stgB(c3, 1, BUF1);
    BAR(); MMQ32(1, 1); BAR();
    // P8: Q10(b) | stage (a+3).A0 -> buf1 (read-done P5); gate tile a+2 complete
    stgA(c3, 0, BUF1);
    BAR(); MMQ32(1, 0);
    VMW6();                 // oldest 8 of 14 = tile a+2; 6 in flight
    BAR();
  }

  // epilogue: bias + store. 32x32 C/D: col=lane&31, row=(r&3)+8*(r>>2)+4*(lane>>5)
  float bv[2];
  #pragma unroll
  for (int nf = 0; nf < 2; ++nf) bv[nf] = bias[n0 + wn * 64 + nf * 32 + l31];
  #pragma unroll
  for (int af = 0; af < 4; ++af) {
    #pragma unroll
    for (int nf = 0; nf < 2; ++nf) {
      const int col = n0 + wn * 64 + nf * 32 + l31;
      #pragma unroll
      for (int q = 0; q < 4; ++q) {
        const int row = m0 + wm * 128 + af * 32 + q * 8 + l5 * 4;
        float* op = out + (size_t)row * N_TOT + col;
        op[0 * (size_t)N_TOT] = acc[af][nf][q * 4 + 0] + bv[nf];
        op[1 * (size_t)N_TOT] = acc[af][nf][q * 4 + 1] + bv[nf];
        op[2 * (size_t)N_TOT] = acc[af][nf][q * 4 + 2] + bv[nf];
        op[3 * (size_t)N_TOT] = acc[af][nf][q * 4 + 3] + bv[nf];
      }
    }
  }
}

extern "C" void kernel_launch(void* const* d_in, const int* in_sizes, int n_in,
                              void* d_out, int out_size, void* d_ws, size_t ws_size,
                              hipStream_t stream) {
  const float* x    = (const float*)d_in[0];
  const float* ss   = (const float*)d_in[1];
  const float* wq   = (const float*)d_in[2];
  const float* la   = (const float*)d_in[3];
  const float* lb   = (const float*)d_in[4];
  const float* wsp  = (const float*)d_in[5];
  const float* bias = (const float*)d_in[6];
  float* out = (float*)d_out;

  uint8_t* w = (uint8_t*)d_ws;
  u16* Ab  = (u16*)w;  w += (size_t)M_TOT * KCAT * 2;    // 130.0 MiB
  u16* Bb  = (u16*)w;  w += (size_t)N_TOT * KCAT * 2;    // 65.0 MiB
  u16* asb = (u16*)w;                                     // 0.25 MiB

  prep_as_k<<<128, 256, 0, stream>>>(la, ss, asb);
  cvt_w_k<<<16384, 256, 0, stream>>>(wq,  Bb, 0);
  cvt_w_k<<<16384, 256, 0, stream>>>(wsp, Bb, K_DIN);
  cvt_lb_k<<<128, 256, 0, stream>>>(lb, Bb);
  prep_x_k<<<M_TOT, 256, 0, stream>>>(x, ss, Ab);
  lora_t_mfma_k<<<M_TOT / 64, 256, 0, stream>>>(Ab, asb);

  hipFuncSetAttribute((const void*)gemm32_k,
                      hipFuncAttributeMaxDynamicSharedMemorySize, 131072);
  gemm32_k<<<dim3((N_TOT / 256) * (M_TOT / 256)), 512, 131072, stream>>>(
      Ab, Bb, bias, out);
}